// Round 9
// baseline (569.735 us; speedup 1.0000x reference)
//
#include <hip/hip_runtime.h>

#define N_NODES_C 50000

// ---------------------------------------------------------------------------
// Detect whether edge_index arrived as int64 (every odd 32-bit word == 0 for
// non-negative values) or int32. All writers store 0 -> benign race.
// ---------------------------------------------------------------------------
__global__ void detect_kernel(const int* __restrict__ w, int ncheck, int* __restrict__ flag) {
    int tid = blockIdx.x * blockDim.x + threadIdx.x;
    if (tid < ncheck) {
        if (w[2 * tid + 1] != 0) *flag = 0;   // found nonzero odd word -> int32
    }
}

// counts[dst]++ over all edges
__global__ void count_kernel(const int* __restrict__ ei, int E, const int* __restrict__ flag,
                             int* __restrict__ counts) {
    int e = blockIdx.x * blockDim.x + threadIdx.x;
    if (e >= E) return;
    int shift = (*flag != 0) ? 1 : 0;
    int d = ei[(unsigned)(E + e) << shift];
    atomicAdd(&counts[d], 1);
}

// Single-block exclusive scan of counts -> row_start (+cursor copy) and
// dis = rsqrt(counts+1) fused in.
__global__ void scan_kernel(const int* __restrict__ counts, int* __restrict__ row_start,
                            int* __restrict__ cursor, float* __restrict__ dis, int n) {
    __shared__ int wsum[16];
    __shared__ int carry;
    __shared__ int chunk_total;
    int tid = threadIdx.x;
    int lane = tid & 63;
    int wid = tid >> 6;
    if (tid == 0) carry = 0;
    __syncthreads();
    for (int base = 0; base < n; base += 1024) {
        int i = base + tid;
        int v = (i < n) ? counts[i] : 0;
        int x = v;
        #pragma unroll
        for (int off = 1; off < 64; off <<= 1) {
            int y = __shfl_up(x, off);
            if (lane >= off) x += y;
        }
        if (lane == 63) wsum[wid] = x;
        __syncthreads();
        if (tid == 0) {
            int run = 0;
            #pragma unroll
            for (int q = 0; q < 16; q++) { int t = wsum[q]; wsum[q] = run; run += t; }
            chunk_total = run;
        }
        __syncthreads();
        int excl = x - v + wsum[wid] + carry;
        if (i < n) {
            row_start[i] = excl;
            cursor[i] = excl;
            dis[i] = rsqrtf((float)v + 1.0f);
        }
        __syncthreads();
        if (tid == 0) carry += chunk_total;
        __syncthreads();
    }
    if (tid == 0) row_start[n] = carry;
}

// Scatter edges into CSR (src only; per-edge weight is computed in agg).
__global__ void fill_kernel(const int* __restrict__ ei, int E, const int* __restrict__ flag,
                            int* __restrict__ cursor, int* __restrict__ csr_src) {
    int e = blockIdx.x * blockDim.x + threadIdx.x;
    if (e >= E) return;
    int shift = (*flag != 0) ? 1 : 0;
    int s = ei[(unsigned)e << shift];
    int d = ei[(unsigned)(E + e) << shift];
    int pos = atomicAdd(&cursor[d], 1);
    csr_src[pos] = s;
}

// ---------------------------------------------------------------------------
// Aggregation over 128-wide rows:
//   out[n,:] = sum_e dis[src_e]*dis[n]*h[src_e,:] + dis[n]^2*h[n,:]
// One wave per node; half-wave (32 lanes x float4) per edge; 4 edges per
// half-wave iteration -> 8 gathers in flight per wave (latency-bound fix).
// ---------------------------------------------------------------------------
template <bool FINAL>
__global__ __launch_bounds__(256) void agg128_kernel(const float* __restrict__ h,
                                                     const int* __restrict__ row_start,
                                                     const int* __restrict__ csr_src,
                                                     const float* __restrict__ dis,
                                                     const float* __restrict__ bmu,
                                                     const float* __restrict__ blog,
                                                     float* __restrict__ out,
                                                     float* __restrict__ outlog, int M) {
    int wid = threadIdx.x >> 6;
    int lane = threadIdx.x & 63;
    int node = blockIdx.x * 4 + wid;
    if (node >= M) return;
    int half = lane >> 5;
    int c0 = (lane & 31) * 4;

    int s = row_start[node];
    int e = row_start[node + 1];
    float dn = dis[node];

    float a0 = 0.f, a1 = 0.f, a2 = 0.f, a3 = 0.f;
    int i = s + half;
    // 4 edges per half-wave per iteration (indices i, i+2, i+4, i+6)
    for (; i + 6 < e; i += 8) {
        int s0 = csr_src[i];
        int s1 = csr_src[i + 2];
        int s2 = csr_src[i + 4];
        int s3 = csr_src[i + 6];
        float w0 = dis[s0] * dn;
        float w1 = dis[s1] * dn;
        float w2 = dis[s2] * dn;
        float w3 = dis[s3] * dn;
        float4 v0 = *(const float4*)&h[(size_t)s0 * 128 + c0];
        float4 v1 = *(const float4*)&h[(size_t)s1 * 128 + c0];
        float4 v2 = *(const float4*)&h[(size_t)s2 * 128 + c0];
        float4 v3 = *(const float4*)&h[(size_t)s3 * 128 + c0];
        a0 = fmaf(w0, v0.x, a0); a1 = fmaf(w0, v0.y, a1);
        a2 = fmaf(w0, v0.z, a2); a3 = fmaf(w0, v0.w, a3);
        a0 = fmaf(w1, v1.x, a0); a1 = fmaf(w1, v1.y, a1);
        a2 = fmaf(w1, v1.z, a2); a3 = fmaf(w1, v1.w, a3);
        a0 = fmaf(w2, v2.x, a0); a1 = fmaf(w2, v2.y, a1);
        a2 = fmaf(w2, v2.z, a2); a3 = fmaf(w2, v2.w, a3);
        a0 = fmaf(w3, v3.x, a0); a1 = fmaf(w3, v3.y, a1);
        a2 = fmaf(w3, v3.z, a2); a3 = fmaf(w3, v3.w, a3);
    }
    for (; i < e; i += 2) {
        int s0 = csr_src[i];
        float w0 = dis[s0] * dn;
        float4 v0 = *(const float4*)&h[(size_t)s0 * 128 + c0];
        a0 = fmaf(w0, v0.x, a0); a1 = fmaf(w0, v0.y, a1);
        a2 = fmaf(w0, v0.z, a2); a3 = fmaf(w0, v0.w, a3);
    }
    // combine the two half-wave partial sums (lane <-> lane^32)
    a0 += __shfl_xor(a0, 32);
    a1 += __shfl_xor(a1, 32);
    a2 += __shfl_xor(a2, 32);
    a3 += __shfl_xor(a3, 32);

    // self-loop term
    float sw = dn * dn;
    float4 sv = *(const float4*)&h[(size_t)node * 128 + c0];
    a0 = fmaf(sw, sv.x, a0); a1 = fmaf(sw, sv.y, a1);
    a2 = fmaf(sw, sv.z, a2); a3 = fmaf(sw, sv.w, a3);

    if (half == 0) {
        if constexpr (FINAL) {
            float b0, b1, b2, b3;
            float* yp;
            if (c0 < 64) {
                b0 = bmu[c0]; b1 = bmu[c0 + 1]; b2 = bmu[c0 + 2]; b3 = bmu[c0 + 3];
                yp = out + (size_t)node * 64 + c0;
            } else {
                int c = c0 - 64;
                b0 = blog[c]; b1 = blog[c + 1]; b2 = blog[c + 2]; b3 = blog[c + 3];
                yp = outlog + (size_t)node * 64 + c;
            }
            float4 o;
            o.x = fmaxf(a0 + b0, 0.f);
            o.y = fmaxf(a1 + b1, 0.f);
            o.z = fmaxf(a2 + b2, 0.f);
            o.w = fmaxf(a3 + b3, 0.f);
            *(float4*)yp = o;
        } else {
            *(float4*)&out[(size_t)node * 128 + c0] = make_float4(a0, a1, a2, a3);
        }
    }
}

// ---------------------------------------------------------------------------
// Dual-branch fused GEMM, v3: k-vectorized LDS reads + transposed W tile.
//   Y[:, 0:N/2] = act( X[:, XA:XA+K] @ Wa + ba )
//   Y[:, N/2:N] = act( X[:, XB:XB+K] @ Wb + bb )
// X row stride LDXS (full row staged in LDS, padded +4 -> bank-rotated).
// W staged TRANSPOSED: wst[col][kk] with stride WTS=KCH+4 so 4 k-steps of one
// col is a single ds_read_b128. Threads own 8 STRIDED cols of one branch
// (col = txl + j*TPB) -> ws reads <=4-way banked, global stores coalesced.
// Per 4 k-steps per thread: RPT+8 x b128 for RPT*32 FMAs.
// ---------------------------------------------------------------------------
template <int K, int N, int LDXS, int XA, int XB, int BM, int KCH, int NT,
          bool RELU, bool BIAS>
__global__ __launch_bounds__(NT) void gemm3_kernel(const float* __restrict__ X,
                                                   const float* __restrict__ Wa,
                                                   const float* __restrict__ Wb,
                                                   const float* __restrict__ ba,
                                                   const float* __restrict__ bb,
                                                   float* __restrict__ Y, int ldy, int M) {
    constexpr int NTX = N / 8;          // threads across cols (8 cols each)
    constexpr int NTY = NT / NTX;       // thread groups down rows
    constexpr int RPT = BM / NTY;       // rows per thread
    constexpr int XLD = LDXS + 4;
    constexpr int NH = N / 2;
    constexpr int WTS = KCH + 4;
    constexpr int TPB = NTX / 2;        // threads per branch; also col stride
    __shared__ alignas(16) float xs[BM * XLD];
    __shared__ alignas(16) float wst[N * WTS];

    int t = threadIdx.x;
    int row0 = blockIdx.x * BM;

    // stage X tile (float4, zero-fill OOB rows)
    constexpr int KQ = LDXS / 4;
    for (int i = t; i < BM * KQ; i += NT) {
        int r = i / KQ, kq = i % KQ;
        float4 v = make_float4(0.f, 0.f, 0.f, 0.f);
        if (row0 + r < M) v = *(const float4*)&X[(size_t)(row0 + r) * LDXS + 4 * kq];
        *(float4*)&xs[r * XLD + 4 * kq] = v;
    }

    int tx = t % NTX;
    int ty = t / NTX;
    int branch = (tx >= TPB) ? 1 : 0;
    int txl = tx - branch * TPB;        // 0..TPB-1
    int xoff = branch ? XB : XA;
    int wbase = (branch * NH + txl) * WTS;

    float acc[RPT][8];
    #pragma unroll
    for (int rr = 0; rr < RPT; rr++)
        #pragma unroll
        for (int j = 0; j < 8; j++) acc[rr][j] = 0.f;

    for (int kc = 0; kc < K; kc += KCH) {
        __syncthreads();   // X ready (first iter) / wst safe to overwrite (later)
        // stage W chunk transposed: wst[c*WTS + kk] = W[kc+kk][c]
        for (int i = t; i < KCH * N; i += NT) {
            int kk = i / N, c = i % N;  // coalesced global read across c
            float v = (c < NH) ? Wa[(size_t)(kc + kk) * NH + c]
                               : Wb[(size_t)(kc + kk) * NH + (c - NH)];
            wst[c * WTS + kk] = v;
        }
        __syncthreads();

        #pragma unroll
        for (int kk4 = 0; kk4 < KCH / 4; ++kk4) {
            float4 wv[8];
            #pragma unroll
            for (int j = 0; j < 8; j++)
                wv[j] = *(const float4*)&wst[wbase + j * (TPB * WTS) + 4 * kk4];
            #pragma unroll
            for (int rr = 0; rr < RPT; rr++) {
                float4 xv = *(const float4*)&xs[(ty * RPT + rr) * XLD + xoff + kc + 4 * kk4];
                #pragma unroll
                for (int j = 0; j < 8; j++) {
                    acc[rr][j] = fmaf(xv.x, wv[j].x, acc[rr][j]);
                    acc[rr][j] = fmaf(xv.y, wv[j].y, acc[rr][j]);
                    acc[rr][j] = fmaf(xv.z, wv[j].z, acc[rr][j]);
                    acc[rr][j] = fmaf(xv.w, wv[j].w, acc[rr][j]);
                }
            }
        }
    }

    // epilogue: 8 strided cols (coalesced across txl per j)
    float bj[8];
    #pragma unroll
    for (int j = 0; j < 8; j++) {
        if constexpr (BIAS) {
            const float* bp = branch ? bb : ba;
            bj[j] = bp[txl + j * TPB];
        } else {
            bj[j] = 0.f;
        }
    }
    #pragma unroll
    for (int rr = 0; rr < RPT; rr++) {
        int row = row0 + ty * RPT + rr;
        if (row < M) {
            float* yp = Y + (size_t)row * ldy + branch * NH + txl;
            #pragma unroll
            for (int j = 0; j < 8; j++) {
                float o = acc[rr][j] + bj[j];
                if constexpr (RELU) o = fmaxf(o, 0.f);
                yp[j * TPB] = o;
            }
        }
    }
}

extern "C" void kernel_launch(void* const* d_in, const int* in_sizes, int n_in,
                              void* d_out, int out_size, void* d_ws, size_t ws_size,
                              hipStream_t stream) {
    const float* x   = (const float*)d_in[0];
    const int*   ei  = (const int*)d_in[1];
    const float* Wm1 = (const float*)d_in[2];  const float* bm1 = (const float*)d_in[3];
    const float* Wm2 = (const float*)d_in[4];  const float* bm2 = (const float*)d_in[5];
    const float* Wm3 = (const float*)d_in[6];  const float* bm3 = (const float*)d_in[7];
    const float* Wl1 = (const float*)d_in[8];  const float* bl1 = (const float*)d_in[9];
    const float* Wl2 = (const float*)d_in[10]; const float* bl2 = (const float*)d_in[11];
    const float* Wl3 = (const float*)d_in[12]; const float* bl3 = (const float*)d_in[13];
    float* out = (float*)d_out;

    const int M = N_NODES_C;
    const int E = in_sizes[1] / 2;

    char* ws = (char*)d_ws;
    size_t off = 0;
    auto alloc = [&](size_t bytes) {
        size_t o = off;
        off += (bytes + 255) & ~(size_t)255;
        return o;
    };
    int*   flag      = (int*)(ws + alloc(4));
    int*   counts    = (int*)(ws + alloc((size_t)M * 4));
    int*   row_start = (int*)(ws + alloc((size_t)(M + 1) * 4));
    int*   cursor    = (int*)(ws + alloc((size_t)M * 4));
    float* dis       = (float*)(ws + alloc((size_t)M * 4));
    int*   csr_src   = (int*)(ws + alloc((size_t)E * 4));
    float* bufA      = (float*)(ws + alloc((size_t)M * 256 * 4));
    float* bufB      = (float*)(ws + alloc((size_t)M * 256 * 4));

    hipMemsetAsync(flag, 1, 4, stream);                 // nonzero -> assume int64
    hipMemsetAsync(counts, 0, (size_t)M * 4, stream);

    int ncheck = (E < 2048) ? E : 2048;
    detect_kernel<<<(ncheck + 255) / 256, 256, 0, stream>>>(ei, ncheck, flag);
    count_kernel<<<(E + 255) / 256, 256, 0, stream>>>(ei, E, flag, counts);
    scan_kernel<<<1, 1024, 0, stream>>>(counts, row_start, cursor, dis, M);
    fill_kernel<<<(E + 255) / 256, 256, 0, stream>>>(ei, E, flag, cursor, csr_src);

    int ablocks = (M + 3) / 4;

    // aggX = A_hat @ x  (pure linear)            x[50000,128] -> bufA[:,0:128]
    agg128_kernel<false><<<ablocks, 256, 0, stream>>>(x, row_start, csr_src, dis,
                                                      nullptr, nullptr, bufA, nullptr, M);

    // layer 1: h1 = relu(aggX @ [Wm1|Wl1] + [bm1|bl1]) -> bufB[:,0:128] (mu64|log64)
    // K=128,N=128,LDXS=128,XA=XB=0,BM=64,KCH=32,NT=256: RPT=4, LDS 52.2KB, 3 blk/CU
    gemm3_kernel<128, 128, 128, 0, 0, 64, 32, 256, true, true>
        <<<(M + 63) / 64, 256, 0, stream>>>(bufA, Wm1, Wl1, bm1, bl1, bufB, 128, M);

    // aggB = A_hat @ h1 (pure)                   bufB[:,0:128] -> bufA[:,0:128]
    agg128_kernel<false><<<ablocks, 256, 0, stream>>>(bufB, row_start, csr_src, dis,
                                                      nullptr, nullptr, bufA, nullptr, M);

    // layer 2 merged: mu = relu(aggB[:,0:64]@Wm2+bm2) -> bufB[:,0:128]
    //                 log = relu(aggB[:,64:128]@Wl2+bl2) -> bufB[:,128:256]
    // K=64,N=256,LDXS=128,XA=0,XB=64,BM=64,KCH=16,NT=256: RPT=8, LDS 54.3KB, 2 blk/CU
    gemm3_kernel<64, 256, 128, 0, 64, 64, 16, 256, true, true>
        <<<(M + 63) / 64, 256, 0, stream>>>(bufA, Wm2, Wl2, bm2, bl2, bufB, 256, M);

    // layer 3 merged (linear only): g_mu = bufB[:,0:128]@Wm3 -> bufA[:,0:64]
    //                               g_log = bufB[:,128:256]@Wl3 -> bufA[:,64:128]
    // K=128,N=128,LDXS=256,XA=0,XB=128,BM=32,KCH=32,NT=128: RPT=4, LDS 51.7KB, 3 blk/CU
    gemm3_kernel<128, 128, 256, 0, 128, 32, 32, 128, false, false>
        <<<(M + 31) / 32, 128, 0, stream>>>(bufB, Wm3, Wl3, nullptr, nullptr, bufA, 128, M);

    // final aggregation + bias + relu, split mu|log into d_out
    agg128_kernel<true><<<ablocks, 256, 0, stream>>>(bufA, row_start, csr_src, dis,
                                                     bm3, bl3, out, out + (size_t)M * 64, M);
}